// Round 8
// baseline (717.359 us; speedup 1.0000x reference)
//
#include <hip/hip_runtime.h>

// ---------------------------------------------------------------------------
// Attention with log-prob bias + mask, outputs (out, p_attn), fp32 I/O.
// B=2, H=8, N=2048, D=64.  bf16 MFMA for QK^T and PV.
//
// R8 = R7's merged-stream experiment, re-expressed without the construct
// that correlates 4/4 with harness "container failed twice" (conditional
// prefetch into ternary-selected vector slots inside an unrolled loop).
// Here: 8 explicit CHUNK() macro invocations, slots A/B token-pasted,
// ALL loads unconditional (last prefetch clamped to chunk 7, dead+valid).
//  - merged read loop: K (L2) + V (L2, early) + P/M (HBM, depth-1 named
//    prefetch at fragment positions) + S^T MFMA + e' + C->A shuffle + PV.
//  - deferred normalization: PV accumulates UNNORMALIZED e' (bf16); O
//    scaled by 1/L at epilogue; out_p = e'*rl in a store-only phase.
//  - LDS 33KB (wred + obuf), 2 barriers total.
// ---------------------------------------------------------------------------

typedef float  f4v   __attribute__((ext_vector_type(4)));
typedef int    i4v   __attribute__((ext_vector_type(4)));
typedef __bf16 bf16x8 __attribute__((ext_vector_type(8)));
typedef unsigned short us8 __attribute__((ext_vector_type(8)));
typedef unsigned short us4 __attribute__((ext_vector_type(4)));
typedef unsigned int   u4v __attribute__((ext_vector_type(4)));
typedef _Float16       h2  __attribute__((ext_vector_type(2)));

#define MFMA16(a,b,c) __builtin_amdgcn_mfma_f32_16x16x32_bf16((a),(b),(c),0,0,0)

static __device__ __forceinline__ unsigned short f2bf(float f){
  unsigned u = __builtin_bit_cast(unsigned, f);
  u += 0x7fffu + ((u >> 16) & 1u);          // RNE to bf16 (inputs are finite)
  return (unsigned short)(u >> 16);
}
static __device__ __forceinline__ bf16x8 ldg8(const unsigned short* p){
  u4v v = *(const u4v*)p;                    // 16B aligned by construction
  return __builtin_bit_cast(bf16x8, v);
}

// ---- prep: Q*0.125 and K to bf16 (row-major, same layout as fp32 source) ---
__global__ void prep_qk(const float* __restrict__ Q, const float* __restrict__ K,
                        unsigned short* __restrict__ Qb, unsigned short* __restrict__ Kb){
  int i = blockIdx.x * 256 + threadIdx.x;
  int base = i * 4;
  f4v q = *(const f4v*)(Q + base);
  f4v k = *(const f4v*)(K + base);
  us4 qo, ko;
#pragma unroll
  for(int j=0;j<4;j++){ qo[j] = f2bf(q[j] * 0.125f); ko[j] = f2bf(k[j]); }
  *(us4*)(Qb + base) = qo;
  *(us4*)(Kb + base) = ko;
}

// ---- prep: V -> bf16 transposed Vt[bh][d][n] via LDS tile transpose --------
__global__ void prep_vt(const float* __restrict__ V, unsigned short* __restrict__ Vt){
  __shared__ unsigned short tile[64][65];
  const int t  = threadIdx.x;                // 256
  const int bh = blockIdx.x >> 5;
  const int n0 = (blockIdx.x & 31) << 6;
  const int r  = t >> 2;
  const int c0 = (t & 3) << 4;
  const float* src = V + (((long)bh*2048 + n0 + r) << 6) + c0;
  f4v vv[4];
#pragma unroll
  for(int i=0;i<4;i++) vv[i] = *(const f4v*)(src + 4*i);
#pragma unroll
  for(int j=0;j<16;j++) tile[r][c0 + j] = f2bf(vv[j>>2][j&3]);
  __syncthreads();
  const int d  = t >> 2;
  const int n8 = (t & 3) << 4;
  us8 o0, o1;
#pragma unroll
  for(int j=0;j<8;j++){ o0[j] = tile[n8 + j][d]; o1[j] = tile[n8 + 8 + j][d]; }
  unsigned short* dst = Vt + (((long)bh*64 + d) << 11) + n0 + n8;
  *(us8*)dst       = o0;
  *(us8*)(dst + 8) = o1;
}

// ---- main fused kernel -----------------------------------------------------
// block = 512 threads (8 waves), 16 q-rows of one (b,h); wave w owns keys
// [w*256,(w+1)*256) = 8 chunks of 32.  S^T trick keeps scores lane-local.
__global__ __launch_bounds__(512, 4) void attn_main(
    const float* __restrict__ P, const int* __restrict__ M,
    const unsigned short* __restrict__ Qb, const unsigned short* __restrict__ Kb,
    const unsigned short* __restrict__ Vt,
    float* __restrict__ out_o, float* __restrict__ out_p){

  __shared__ float wred[8][16];              // per-wave row sums
  __shared__ float obuf[8][16][64];          // unnormalized O partials (32KB)

  const int tid  = threadIdx.x;
  const int w    = tid >> 6;
  const int lane = tid & 63;
  const int m    = lane & 15;                // qrow index (C-layout col)
  const int q    = lane >> 4;                // quad
  const int bidx = blockIdx.x;
  // XCD-swizzle: bidx%8 -> XCD; heads {2x,2x+1} pinned per XCD for K/V L2 reuse
  const int bh = ((bidx & 7) << 1) | ((bidx >> 3) & 1);
  const int qt = bidx >> 4;
  const int q0 = qt << 4;
  const int wbase = w << 8;                  // 256 keys per wave

  const long  rowQ  = (long)bh*2048 + q0 + m;
  const long  pbase = rowQ * 2048;
  const unsigned short* Qrow = Qb + rowQ * 64;
  const bf16x8 qf0 = ldg8(Qrow + q*8);       // Q[row m][d 8q+j], d 0..31
  const bf16x8 qf1 = ldg8(Qrow + 32 + q*8);  // d 32..63
  const unsigned short* Kbh = Kb + ((long)bh << 17);
  const unsigned short* Vbh = Vt + ((long)bh << 17);

  // P/M at fragment positions: lane (m,q) covers cols {4q..4q+3, 16+4q..+3}.
  const float* ppb = P + pbase + wbase + 4*q;
  const int*   mpb = M + pbase + wbase + 4*q;

  // depth-1 named prefetch slots (all defs unconditional; no vector ternaries)
  f4v pLA, pHA, pLB, pHB;
  i4v mLA, mHA, mLB, mHB;
  pLA = *(const f4v*)(ppb);
  pHA = *(const f4v*)(ppb + 16);
  mLA = *(const i4v*)(mpb);
  mHA = *(const i4v*)(mpb + 16);

  h2 eh[8][4];                               // e' = (p+eps)*exp(S-12), fp16
  float l0 = 0.f, l1 = 0.f;
  f4v o0={0.f,0.f,0.f,0.f}, o1={0.f,0.f,0.f,0.f}, o2={0.f,0.f,0.f,0.f}, o3={0.f,0.f,0.f,0.f};
  const bool qodd = (q & 1) != 0;
  const bool qmid = (q == 1) || (q == 2);

  // One chunk: K,V loads (L2) + unconditional P/M prefetch into slot NXT +
  // S^T MFMA + e' from slot CUR + C->A shuffle + PV accumulate.
#define CHUNK(c, CUR, NXT, cn) { \
    const int k0g = wbase + (c)*32; \
    const unsigned short* Kp = Kbh + (long)(k0g + m)*64 + q*8; \
    bf16x8 kf00 = ldg8(Kp); \
    bf16x8 kf01 = ldg8(Kp + 32); \
    bf16x8 kf10 = ldg8(Kp + 16*64); \
    bf16x8 kf11 = ldg8(Kp + 16*64 + 32); \
    const unsigned short* Vp = Vbh + (long)m*2048 + k0g + q*8; \
    bf16x8 vf0 = ldg8(Vp); \
    bf16x8 vf1 = ldg8(Vp + 16*2048); \
    bf16x8 vf2 = ldg8(Vp + 32*2048); \
    bf16x8 vf3 = ldg8(Vp + 48*2048); \
    pL##NXT = *(const f4v*)(ppb + (cn)*32); \
    pH##NXT = *(const f4v*)(ppb + (cn)*32 + 16); \
    mL##NXT = *(const i4v*)(mpb + (cn)*32); \
    mH##NXT = *(const i4v*)(mpb + (cn)*32 + 16); \
    f4v acc0 = {0.f,0.f,0.f,0.f}, acc1 = {0.f,0.f,0.f,0.f}; \
    acc0 = MFMA16(kf00, qf0, acc0); \
    acc0 = MFMA16(kf01, qf1, acc0); \
    acc1 = MFMA16(kf10, qf0, acc1); \
    acc1 = MFMA16(kf11, qf1, acc1); \
    float ev0 = (mL##CUR[0]==0) ? 0.f : (pL##CUR[0] + 1e-12f) * __expf(acc0[0] - 12.0f); \
    float ev1 = (mL##CUR[1]==0) ? 0.f : (pL##CUR[1] + 1e-12f) * __expf(acc0[1] - 12.0f); \
    float ev2 = (mL##CUR[2]==0) ? 0.f : (pL##CUR[2] + 1e-12f) * __expf(acc0[2] - 12.0f); \
    float ev3 = (mL##CUR[3]==0) ? 0.f : (pL##CUR[3] + 1e-12f) * __expf(acc0[3] - 12.0f); \
    float ev4 = (mH##CUR[0]==0) ? 0.f : (pH##CUR[0] + 1e-12f) * __expf(acc1[0] - 12.0f); \
    float ev5 = (mH##CUR[1]==0) ? 0.f : (pH##CUR[1] + 1e-12f) * __expf(acc1[1] - 12.0f); \
    float ev6 = (mH##CUR[2]==0) ? 0.f : (pH##CUR[2] + 1e-12f) * __expf(acc1[2] - 12.0f); \
    float ev7 = (mH##CUR[3]==0) ? 0.f : (pH##CUR[3] + 1e-12f) * __expf(acc1[3] - 12.0f); \
    l0 += ev0 + ev2 + ev4 + ev6; \
    l1 += ev1 + ev3 + ev5 + ev7; \
    { h2 t; t[0]=(_Float16)ev0; t[1]=(_Float16)ev1; eh[(c)][0]=t; } \
    { h2 t; t[0]=(_Float16)ev2; t[1]=(_Float16)ev3; eh[(c)][1]=t; } \
    { h2 t; t[0]=(_Float16)ev4; t[1]=(_Float16)ev5; eh[(c)][2]=t; } \
    { h2 t; t[0]=(_Float16)ev6; t[1]=(_Float16)ev7; eh[(c)][3]=t; } \
    float t0=__shfl_xor(ev0,16), t1=__shfl_xor(ev1,16), \
          t2=__shfl_xor(ev2,16), t3=__shfl_xor(ev3,16), \
          t4=__shfl_xor(ev4,16), t5=__shfl_xor(ev5,16), \
          t6=__shfl_xor(ev6,16), t7=__shfl_xor(ev7,16); \
    float s10 = qodd ? t4 : ev0;  float s11 = qodd ? t5 : ev1; \
    float s12 = qodd ? t6 : ev2;  float s13 = qodd ? t7 : ev3; \
    float s14 = qodd ? ev4 : t0;  float s15 = qodd ? ev5 : t1; \
    float s16 = qodd ? ev6 : t2;  float s17 = qodd ? ev7 : t3; \
    float u0=__shfl_xor(s10,48), u1=__shfl_xor(s11,48), \
          u2=__shfl_xor(s12,48), u3=__shfl_xor(s13,48), \
          u4=__shfl_xor(s14,48), u5=__shfl_xor(s15,48), \
          u6=__shfl_xor(s16,48), u7=__shfl_xor(s17,48); \
    us8 pb; \
    pb[0] = f2bf(qmid ? u0 : s10);  pb[1] = f2bf(qmid ? u1 : s11); \
    pb[2] = f2bf(qmid ? u2 : s12);  pb[3] = f2bf(qmid ? u3 : s13); \
    pb[4] = f2bf(qmid ? u4 : s14);  pb[5] = f2bf(qmid ? u5 : s15); \
    pb[6] = f2bf(qmid ? u6 : s16);  pb[7] = f2bf(qmid ? u7 : s17); \
    bf16x8 af = __builtin_bit_cast(bf16x8, pb); \
    o0 = MFMA16(af, vf0, o0); \
    o1 = MFMA16(af, vf1, o1); \
    o2 = MFMA16(af, vf2, o2); \
    o3 = MFMA16(af, vf3, o3); \
  }

  // 8 chunks, alternating slots; last prefetch clamped to 7 (valid, dead)
  CHUNK(0, A, B, 1)
  CHUNK(1, B, A, 2)
  CHUNK(2, A, B, 3)
  CHUNK(3, B, A, 4)
  CHUNK(4, A, B, 5)
  CHUNK(5, B, A, 6)
  CHUNK(6, A, B, 7)
  CHUNK(7, B, A, 7)
#undef CHUNK

  // ------- row sum (quad shuffle + cross-wave LDS, single barrier) ---------
  float l = l0 + l1;
  l += __shfl_xor(l, 16);
  l += __shfl_xor(l, 32);
  if(lane < 16) wred[w][lane] = l;
  __syncthreads();
  float L = 0.f;
#pragma unroll
  for(int i=0;i<8;i++) L += wred[i][m];
  const float rl = 1.0f / L;                 // for qrow m (out_p path)

  // ------- phase C: store-only out_p = e'*rl (fire-and-forget) -------------
  float* opb = out_p + pbase + wbase + 4*q;
#pragma unroll
  for(int c=0;c<8;c++){
    f4v lo, hi;
#pragma unroll
    for(int i=0;i<4;i++){
      lo[i] = (float)eh[c][i>>1][i&1] * rl;          // ev[0..3]
      hi[i] = (float)eh[c][(4+i)>>1][(4+i)&1] * rl;  // ev[4..7]
    }
    *(f4v*)(opb + c*32)      = lo;
    *(f4v*)(opb + c*32 + 16) = hi;
  }

  // ------- O: cross-wave sum, normalize by 1/L_row at epilogue -------------
#pragma unroll
  for(int r=0;r<4;r++){
    obuf[w][4*q + r][m]      = o0[r];
    obuf[w][4*q + r][16 + m] = o1[r];
    obuf[w][4*q + r][32 + m] = o2[r];
    obuf[w][4*q + r][48 + m] = o3[r];
  }
  __syncthreads();
  if(tid < 256){
    const int row = tid >> 4, cg = (tid & 15) << 2;
    f4v s = {0.f,0.f,0.f,0.f};
#pragma unroll
    for(int i=0;i<8;i++) s += *(const f4v*)&obuf[i][row][cg];
    float Lr = 0.f;
#pragma unroll
    for(int i=0;i<8;i++) Lr += wred[i][row];
    s *= (1.0f / Lr);
    *(f4v*)(out_o + ((long)bh*2048 + q0 + row)*64 + cg) = s;
  }
}

// ---------------------------------------------------------------------------
extern "C" void kernel_launch(void* const* d_in, const int* in_sizes, int n_in,
                              void* d_out, int out_size, void* d_ws, size_t ws_size,
                              hipStream_t stream){
  const float* Q = (const float*)d_in[0];
  const float* K = (const float*)d_in[1];
  const float* V = (const float*)d_in[2];
  const int*   M = (const int*)  d_in[3];
  const float* P = (const float*)d_in[4];

  float* out_o = (float*)d_out;                       // [2,8,2048,64]
  float* out_p = out_o + (size_t)2*8*2048*64;         // [2,8,2048,2048]

  unsigned short* Qb = (unsigned short*)d_ws;         // 4MB
  unsigned short* Kb = Qb + (size_t)2*8*2048*64;      // 4MB
  unsigned short* Vt = Kb + (size_t)2*8*2048*64;      // 4MB (transposed)

  prep_qk<<<2048, 256, 0, stream>>>(Q, K, Qb, Kb);
  prep_vt<<<512, 256, 0, stream>>>(V, Vt);
  attn_main<<<2048, 512, 0, stream>>>(P, M, Qb, Kb, Vt, out_o, out_p);
}